// Round 1
// baseline (272.152 us; speedup 1.0000x reference)
//
#include <hip/hip_runtime.h>
#include <hip/hip_bf16.h>

constexpr int kS   = 32;
constexpr int kB   = 256;
constexpr int kIN  = 1024;
constexpr int kOUT = 1024;

typedef __bf16 v4bf __attribute__((ext_vector_type(4)));
typedef __bf16 v8bf __attribute__((ext_vector_type(8)));
typedef float  v4f  __attribute__((ext_vector_type(4)));

__device__ __forceinline__ float softplus_f(float x) {
    // stable: max(x,0) + log1p(exp(-|x|))
    return fmaxf(x, 0.0f) + log1pf(expf(-fabsf(x)));
}

__device__ __forceinline__ v4bf cvt4(float4 v) {
    v4bf r;
    r.x = (__bf16)v.x; r.y = (__bf16)v.y; r.z = (__bf16)v.z; r.w = (__bf16)v.w;
    return r;
}

// sigma_w = softplus(weight_rho), OUT*IN elements
__global__ void sigma_kernel(const float* __restrict__ rho, float* __restrict__ sigma) {
    int i = blockIdx.x * blockDim.x + threadIdx.x;
    sigma[i] = softplus_f(rho[i]);
}

// bias_s[s][o] = bias_mu[o] + softplus(bias_rho[o]) * eps_b[s][o], S*OUT elements
__global__ void bias_kernel(const float* __restrict__ b_mu, const float* __restrict__ b_rho,
                            const float* __restrict__ eps_b, float* __restrict__ bias_s) {
    int i = blockIdx.x * blockDim.x + threadIdx.x;  // i = s*OUT + o
    int o = i & (kOUT - 1);
    bias_s[i] = fmaf(softplus_f(b_rho[o]), eps_b[i], b_mu[o]);
}

// Main: per block (s, o_tile of 64): out[s, 0:256, o_base:o_base+64]
//   = X[s] (256x1024) @ W[s,o_tile]^T (64x1024) + bias_s
// W materialized inline: w = mu + sigma * eps, cast to bf16.
__global__ __launch_bounds__(256) void dv_main(
        const float* __restrict__ X,     // [S][B][IN]
        const float* __restrict__ Wmu,   // [OUT][IN]
        const float* __restrict__ Wsig,  // [OUT][IN]
        const float* __restrict__ Ew,    // [S][OUT][IN]
        const float* __restrict__ Bs,    // [S][OUT]
        float* __restrict__ O)           // [S][B][OUT]
{
    constexpr int LS = 40;  // LDS row stride in bf16 (80 B): 16B-aligned frag reads, spread banks
    __shared__ __attribute__((aligned(16))) __bf16 Xs[256 * LS];  // 20.0 KB
    __shared__ __attribute__((aligned(16))) __bf16 Ws[64 * LS];   //  5.0 KB

    const int tid    = threadIdx.x;
    const int ot     = blockIdx.x;       // 0..15
    const int s      = blockIdx.y;       // 0..31
    const int o_base = ot * 64;
    const int lane   = tid & 63;
    const int wv     = tid >> 6;         // wave 0..3
    const int lr     = lane & 15;
    const int kg     = lane >> 4;        // k-group 0..3
    const int m_base = wv * 64;

    const float* Xg = X   + (size_t)s * kB * kIN;
    const float* Eg = Ew  + ((size_t)s * kOUT + o_base) * kIN;
    const float* Mg = Wmu + (size_t)o_base * kIN;
    const float* Sg = Wsig + (size_t)o_base * kIN;

    v4f acc[4][4] = {};

    for (int kk = 0; kk < kIN; kk += 32) {
        // --- stage X tile: 256 rows x 32 k = 2048 float4, 8 per thread ---
        #pragma unroll
        for (int j = 0; j < 8; ++j) {
            int f   = j * 256 + tid;
            int row = f >> 3;       // 0..255
            int kq  = f & 7;        // float4 index in BK
            float4 v = *reinterpret_cast<const float4*>(Xg + (size_t)row * kIN + kk + kq * 4);
            *reinterpret_cast<v4bf*>(&Xs[row * LS + kq * 4]) = cvt4(v);
        }
        // --- stage W tile: 64 rows x 32 k = 512 float4, 2 per thread ---
        #pragma unroll
        for (int j = 0; j < 2; ++j) {
            int f   = j * 256 + tid;
            int row = f >> 3;       // 0..63
            int kq  = f & 7;
            size_t idx = (size_t)row * kIN + kk + kq * 4;
            float4 e = *reinterpret_cast<const float4*>(Eg + idx);
            float4 m = *reinterpret_cast<const float4*>(Mg + idx);
            float4 g = *reinterpret_cast<const float4*>(Sg + idx);
            float4 w;
            w.x = fmaf(g.x, e.x, m.x);
            w.y = fmaf(g.y, e.y, m.y);
            w.z = fmaf(g.z, e.z, m.z);
            w.w = fmaf(g.w, e.w, m.w);
            *reinterpret_cast<v4bf*>(&Ws[row * LS + kq * 4]) = cvt4(w);
        }
        __syncthreads();

        v8bf a[4], b[4];
        #pragma unroll
        for (int mf = 0; mf < 4; ++mf)
            a[mf] = *reinterpret_cast<const v8bf*>(&Xs[(m_base + mf * 16 + lr) * LS + kg * 8]);
        #pragma unroll
        for (int nf = 0; nf < 4; ++nf)
            b[nf] = *reinterpret_cast<const v8bf*>(&Ws[(nf * 16 + lr) * LS + kg * 8]);
        #pragma unroll
        for (int mf = 0; mf < 4; ++mf) {
            #pragma unroll
            for (int nf = 0; nf < 4; ++nf)
                acc[mf][nf] = __builtin_amdgcn_mfma_f32_16x16x32_bf16(a[mf], b[nf], acc[mf][nf], 0, 0, 0);
        }
        __syncthreads();
    }

    // --- epilogue: add sampled bias, store ---
    float bias[4];
    #pragma unroll
    for (int nf = 0; nf < 4; ++nf)
        bias[nf] = Bs[(size_t)s * kOUT + o_base + nf * 16 + lr];

    #pragma unroll
    for (int mf = 0; mf < 4; ++mf) {
        #pragma unroll
        for (int r = 0; r < 4; ++r) {
            int brow = m_base + mf * 16 + kg * 4 + r;   // C/D: row=(lane>>4)*4+reg
            float* orow = O + ((size_t)s * kB + brow) * kOUT + o_base;
            #pragma unroll
            for (int nf = 0; nf < 4; ++nf)
                orow[nf * 16 + lr] = acc[mf][nf][r] + bias[nf];  // col = lane&15
        }
    }
}

extern "C" void kernel_launch(void* const* d_in, const int* in_sizes, int n_in,
                              void* d_out, int out_size, void* d_ws, size_t ws_size,
                              hipStream_t stream) {
    const float* input = (const float*)d_in[0];   // (S,B,IN)
    const float* w_mu  = (const float*)d_in[1];   // (OUT,IN)
    const float* w_rho = (const float*)d_in[2];   // (OUT,IN)
    const float* b_mu  = (const float*)d_in[3];   // (OUT,)
    const float* b_rho = (const float*)d_in[4];   // (OUT,)
    const float* eps_w = (const float*)d_in[5];   // (S,OUT,IN)
    const float* eps_b = (const float*)d_in[6];   // (S,OUT)
    float* out = (float*)d_out;                   // (S,B,OUT) fp32

    float* sigma  = (float*)d_ws;                        // OUT*IN fp32 = 4 MB
    float* bias_s = sigma + (size_t)kOUT * kIN;          // S*OUT fp32 = 128 KB

    sigma_kernel<<<dim3((kOUT * kIN) / 256), 256, 0, stream>>>(w_rho, sigma);
    bias_kernel<<<dim3((kS * kOUT) / 256), 256, 0, stream>>>(b_mu, b_rho, eps_b, bias_s);

    dim3 grid(kOUT / 64, kS);
    dv_main<<<grid, 256, 0, stream>>>(input, w_mu, sigma, eps_w, bias_s, out);
}